// Round 1
// baseline (1447.287 us; speedup 1.0000x reference)
//
#include <hip/hip_runtime.h>

// AttentivePooling: h = tanh(x@W1+b1); s = h@W2+b2; per-graph softmax(s); out = seg_sum(w*x)
// N=1048576 nodes, HID=256, G=2048 graphs, batch sorted.
//
// Strategy: single pass over x (1.07 GB -> ~170us HBM floor) with flash-style
// online segment softmax. Scoring via bf16 MFMA (16x16x32) so compute hides
// under the HBM stream. One block per graph (batch is sorted => contiguous).

#define HID   256
#define HHID  128
#define TILE  128          // nodes per LDS tile
#define BLK   512          // threads per main block (8 waves)
#define PITCH 264          // bf16 elems per LDS row: 256 + 8 pad (132 dwords % 32 = 4 -> 2-way = free)

typedef __attribute__((ext_vector_type(8))) short short8;
typedef __attribute__((ext_vector_type(4))) float f32x4;

__device__ __forceinline__ unsigned short f2bf(float f) {
  unsigned u = __builtin_bit_cast(unsigned, f);
  u += 0x7fffu + ((u >> 16) & 1u);           // RNE
  return (unsigned short)(u >> 16);
}
__device__ __forceinline__ float bf2f(unsigned short s) {
  unsigned u = ((unsigned)s) << 16;
  return __builtin_bit_cast(float, u);
}

// ---------------- prep: W1^T -> bf16 in ws, and segment starts ----------------
__global__ void prep_kernel(const float* __restrict__ W1,   // [256][128]
                            const int* __restrict__ batch,  // [N], sorted
                            unsigned short* __restrict__ w1t, // [128][256] bf16
                            int* __restrict__ starts,       // [G+1]
                            int n, int g) {
  int tid = blockIdx.x * blockDim.x + threadIdx.x;
  if (tid < HID * HHID) {
    int k = tid / HHID, j = tid % HHID;
    w1t[j * HID + k] = f2bf(W1[tid]);
  }
  if (tid < n) {
    int b = batch[tid];
    int prev = (tid == 0) ? -1 : batch[tid - 1];
    for (int q = prev + 1; q <= b; ++q) starts[q] = tid;
    if (tid == n - 1)
      for (int q = b + 1; q <= g; ++q) starts[q] = n;
  }
}

// ---------------- main: one block per graph ----------------
__global__ __launch_bounds__(BLK, 2) void pool_kernel(
    const float* __restrict__ x,            // [N][256]
    const int* __restrict__ starts,         // [G+1]
    const float* __restrict__ b1,           // [128]
    const float* __restrict__ W2,           // [128]
    const float* __restrict__ b2,           // [1]
    const unsigned short* __restrict__ w1t, // [128][256] bf16
    float* __restrict__ out)                // [G][256]
{
  __shared__ __align__(16) unsigned short lds_w1t[HHID * PITCH]; // 67.6 KB
  __shared__ __align__(16) unsigned short lds_x[TILE * PITCH];   // 67.6 KB (reused as f32 in epilogue)
  __shared__ float lds_sc[TILE];     // scores, then e
  __shared__ float lds_b1[HHID];
  __shared__ float lds_w2[HHID];
  __shared__ float lds_state[4];     // 0:m  1:l  2:alpha

  const int t    = threadIdx.x;
  const int g    = blockIdx.x;
  const int lane = t & 63;
  const int wave = t >> 6;

  // stage W1^T (rows contiguous; pad-aware)
  for (int i = t; i < (HHID * HID) / 8; i += BLK) {
    int row = i >> 5, c8 = (i & 31) << 3;
    short8 v = *(const short8*)(w1t + row * HID + c8);
    *(short8*)(&lds_w1t[row * PITCH + c8]) = v;
  }
  if (t < HHID) { lds_b1[t] = b1[t]; lds_w2[t] = W2[t]; }
  if (t == 0)   { lds_state[0] = -1e30f; lds_state[1] = 0.f; lds_state[2] = 0.f; }

  const int start = starts[g], end = starts[g + 1];
  const int cnt = end - start;
  const float b2v = b2[0];

  // per-thread pooled partials: channels 8*(t&31)..+7, node-slice sl = t>>5
  const int cg = (t & 31) << 3;
  const int sl = t >> 5;
  float opart[8];
#pragma unroll
  for (int j = 0; j < 8; ++j) opart[j] = 0.f;

  __syncthreads();

  if (cnt > 0) {
    const int ntiles = (cnt + TILE - 1) / TILE;
    f32x4 pre[16]; // next tile, 64 floats/thread

    auto load_tile = [&](int tbase) {
#pragma unroll
      for (int k2 = 0; k2 < 8; ++k2) {
        int item = t + k2 * BLK;        // 0..4095
        int row  = item >> 5;
        int c8   = (item & 31) << 3;
        int node = start + tbase + row;
        if (node < end) {
          const float* p = x + (size_t)node * HID + c8;
          pre[2 * k2]     = *(const f32x4*)p;
          pre[2 * k2 + 1] = *(const f32x4*)(p + 4);
        } else {
          pre[2 * k2]     = (f32x4){0.f, 0.f, 0.f, 0.f};
          pre[2 * k2 + 1] = (f32x4){0.f, 0.f, 0.f, 0.f};
        }
      }
    };

    load_tile(0);

    for (int tb = 0; tb < ntiles; ++tb) {
      const int tbase = tb * TILE;

      __syncthreads();   // prev tile's accumulate done with lds_x / lds_sc
      // registers -> bf16 LDS tile
#pragma unroll
      for (int k2 = 0; k2 < 8; ++k2) {
        int item = t + k2 * BLK;
        int row  = item >> 5;
        int c8   = (item & 31) << 3;
        short8 v;
#pragma unroll
        for (int q = 0; q < 8; ++q) {
          float f = (q < 4) ? pre[2 * k2][q] : pre[2 * k2 + 1][q - 4];
          v[q] = (short)f2bf(f);
        }
        *(short8*)(&lds_x[row * PITCH + c8]) = v;
      }
      __syncthreads();   // lds_x ready

      // prefetch next tile into registers (overlaps with MFMA below)
      if (tb + 1 < ntiles) load_tile(tbase + TILE);

      // ---- scoring: wave w owns row-tile w (16 nodes), all 8 col-tiles ----
      short8 afrag[8];
      const int arow = wave * 16 + (lane & 15);
      const int kq   = (lane >> 4) << 3;  // quad*8
#pragma unroll
      for (int s = 0; s < 8; ++s)
        afrag[s] = *(const short8*)(&lds_x[arow * PITCH + s * 32 + kq]);

      float p[4] = {0.f, 0.f, 0.f, 0.f};
      const int bj = lane & 15;
#pragma unroll
      for (int c = 0; c < 8; ++c) {
        f32x4 acc = {0.f, 0.f, 0.f, 0.f};
#pragma unroll
        for (int s = 0; s < 8; ++s) {
          short8 bfrag = *(const short8*)(&lds_w1t[(c * 16 + bj) * PITCH + s * 32 + kq]);
          acc = __builtin_amdgcn_mfma_f32_16x16x32_bf16(afrag[s], bfrag, acc, 0, 0, 0);
        }
        int col = c * 16 + bj;
        float b1v = lds_b1[col], w2v = lds_w2[col];
#pragma unroll
        for (int r = 0; r < 4; ++r) {
          float h  = acc[r] + b1v;
          float e2 = __expf(2.f * h);          // tanh via exp
          float th = (e2 - 1.f) / (e2 + 1.f);
          p[r] += th * w2v;
        }
      }
      // butterfly sum over the 16 columns (low 4 lane bits)
#pragma unroll
      for (int m = 1; m <= 8; m <<= 1) {
#pragma unroll
        for (int r = 0; r < 4; ++r) p[r] += __shfl_xor(p[r], m, 64);
      }
      {
        int r = lane & 15;
        if (r < 4) {
          int nl = wave * 16 + ((lane >> 4) << 2) + r;
          float pr = (r == 0) ? p[0] : (r == 1) ? p[1] : (r == 2) ? p[2] : p[3];
          int node = start + tbase + nl;
          lds_sc[nl] = (node < end) ? (pr + b2v) : -1e30f;
        }
      }
      __syncthreads();   // scores ready

      // ---- wave 0: online softmax state update ----
      if (wave == 0) {
        float s0 = lds_sc[lane], s1 = lds_sc[lane + 64];
        float mx = fmaxf(s0, s1);
#pragma unroll
        for (int m = 1; m <= 32; m <<= 1) mx = fmaxf(mx, __shfl_xor(mx, m, 64));
        float mold = lds_state[0];
        float mnew = fmaxf(mold, mx);
        float alpha = __expf(mold - mnew);
        float e0 = __expf(s0 - mnew), e1 = __expf(s1 - mnew);
        lds_sc[lane] = e0; lds_sc[lane + 64] = e1;
        float es = e0 + e1;
#pragma unroll
        for (int m = 1; m <= 32; m <<= 1) es += __shfl_xor(es, m, 64);
        if (lane == 0) {
          lds_state[1] = lds_state[1] * alpha + es;
          lds_state[0] = mnew;
          lds_state[2] = alpha;
        }
      }
      __syncthreads();   // e + alpha ready

      // ---- accumulate O += e * x (bf16 tile) ----
      {
        float alpha = lds_state[2];
#pragma unroll
        for (int j = 0; j < 8; ++j) opart[j] *= alpha;
#pragma unroll
        for (int it = 0; it < TILE / 16; ++it) {
          int n = sl + it * 16;
          float e = lds_sc[n];
          short8 xv = *(const short8*)(&lds_x[n * PITCH + cg]);
#pragma unroll
          for (int j = 0; j < 8; ++j)
            opart[j] = fmaf(e, bf2f((unsigned short)xv[j]), opart[j]);
        }
      }
    }
  }

  // ---------------- epilogue: reduce 16 slices, divide by l ----------------
  __syncthreads();
  float* red = (float*)lds_x;    // [16][256]
  {
    f32x4 a = {opart[0], opart[1], opart[2], opart[3]};
    f32x4 b = {opart[4], opart[5], opart[6], opart[7]};
    *(f32x4*)(&red[sl * HID + cg])     = a;
    *(f32x4*)(&red[sl * HID + cg + 4]) = b;
  }
  __syncthreads();
#pragma unroll
  for (int st = 8; st >= 1; st >>= 1) {
    if (sl < st) {
#pragma unroll
      for (int j = 0; j < 8; ++j)
        red[sl * HID + cg + j] += red[(sl + st) * HID + cg + j];
    }
    __syncthreads();
  }
  if (t < 64) {
    float l = lds_state[1];
    float inv = (cnt > 0) ? 1.f / l : 0.f;
    f32x4 o;
#pragma unroll
    for (int j = 0; j < 4; ++j) o[j] = red[t * 4 + j] * inv;
    *(f32x4*)(out + (size_t)g * HID + t * 4) = o;
  }
}

extern "C" void kernel_launch(void* const* d_in, const int* in_sizes, int n_in,
                              void* d_out, int out_size, void* d_ws, size_t ws_size,
                              hipStream_t stream) {
  const float* x     = (const float*)d_in[0];
  const int*   batch = (const int*)d_in[1];
  const float* W1    = (const float*)d_in[2];
  const float* b1    = (const float*)d_in[3];
  const float* W2    = (const float*)d_in[4];
  const float* b2    = (const float*)d_in[5];
  float* out = (float*)d_out;

  const int n = in_sizes[0] / HID;   // 1048576
  const int g = out_size / HID;      // 2048

  unsigned short* w1t = (unsigned short*)d_ws;
  int* starts = (int*)((char*)d_ws + (size_t)HID * HHID * sizeof(unsigned short));

  prep_kernel<<<(n + 255) / 256, 256, 0, stream>>>(W1, batch, w1t, starts, n, g);
  pool_kernel<<<g, BLK, 0, stream>>>(x, starts, b1, W2, b2, w1t, out);
}